// Round 1
// baseline (169.760 us; speedup 1.0000x reference)
//
#include <hip/hip_runtime.h>

// KPConv as bf16 MFMA GEMM: OUT[p,o] = sum_j C[p,j] * W2[j,o]
//   j = k*3+i (48, padded to 64), C[p,j] = g[p,k]*x[p,i], W2 = weights flat [48][64].
// Block = 256 threads = 256 points. Phase A: per-thread C-row -> LDS in MFMA
// fragment layout. Phase B: 4 waves x 4 tiles, OPERAND-SWAPPED MFMA so D = OUT^T
// tile: lane holds out[p][o..o+3] contiguous -> float4 nontemporal stores.
// No __syncthreads: dataflow is purely intra-wave (wave wv's lanes compute
// exactly the 4 tiles it consumes), so a wave-local lgkmcnt(0) suffices.

typedef __bf16  bf16x8 __attribute__((ext_vector_type(8)));
typedef float   f32x4  __attribute__((ext_vector_type(4)));
typedef unsigned int   u32x4  __attribute__((ext_vector_type(4)));

union OctU {
    unsigned short s[8];
    u32x4          u4;
    bf16x8         v;
};

__global__ __launch_bounds__(256) void kpconv_mfma(
    const float* __restrict__ x,       // [P][3]
    const float* __restrict__ kp,      // [16][3]
    const float* __restrict__ w,       // [48][64] (= [16][3][64])
    const float* __restrict__ sigma,   // [1]
    float* __restrict__ out)           // [P][64]
{
    // 2048 chunks of 16B (16 tiles * 2 khalf * 4 quad * 16 m) + pad every 8
    __shared__ u32x4 ldsA[2304];

    const int tid  = threadIdx.x;
    const int lane = tid & 63;
    const int wv   = tid >> 6;
    const int q    = lane >> 4;   // quad within wave
    const int n16  = lane & 15;
    const long long base = (long long)blockIdx.x * 256;

    // ---- W fragments (weights), resident in VGPRs for the whole block ----
    // Same data as before, but now used as the MFMA *A* operand (A/B lane
    // layouts are symmetric): A'[row = ot*16+n16 -> o][k = h*32+q*8+j -> j'].
    bf16x8 wfrag[2][4];
#pragma unroll
    for (int h = 0; h < 2; ++h) {
#pragma unroll
        for (int ot = 0; ot < 4; ++ot) {
            OctU o;
#pragma unroll
            for (int j = 0; j < 8; ++j) {
                int kk = h * 32 + q * 8 + j;
                float v = (kk < 48) ? w[kk * 64 + ot * 16 + n16] : 0.0f;
                o.v[j] = (__bf16)v;   // native cast -> v_cvt_pk_bf16_f32 pairs
            }
            wfrag[h][ot] = o.v;
        }
    }

    // ---- Phase A: this thread's point -> bf16 C-row in LDS ----
    {
        const float sg = sigma[0];
        // exp(-0.5*d2/s^2) = exp2(d2 * (-0.5*log2e)/s^2)
        const float scale = -0.72134752f / (sg * sg);
        const long long p = base + tid;
        float xv[3];
        xv[0] = x[p * 3 + 0];
        xv[1] = x[p * 3 + 1];
        xv[2] = x[p * 3 + 2];
        float g[16];
#pragma unroll
        for (int k = 0; k < 16; ++k) {
            float dx = xv[0] - kp[k * 3 + 0];
            float dy = xv[1] - kp[k * 3 + 1];
            float dz = xv[2] - kp[k * 3 + 2];
            float d2 = dx * dx + dy * dy + dz * dz;
            g[k] = exp2f(d2 * scale);
        }
        const int tile = tid >> 4;
        const int m    = tid & 15;
#pragma unroll
        for (int o = 0; o < 8; ++o) {      // octet o covers j = 8o..8o+7
            OctU ou;
#pragma unroll
            for (int j8 = 0; j8 < 8; ++j8) {
                int j = o * 8 + j8;
                ou.v[j8] = (j < 48) ? (__bf16)(g[j / 3] * xv[j % 3])
                                    : (__bf16)0.0f;  // zero K-pad (LDS is poison!)
            }
            int chunk = tile * 128 + (o >> 2) * 64 + (o & 3) * 16 + m;
            ldsA[chunk + (chunk >> 3)] = ou.u4;
        }
    }

    // Intra-wave producer->consumer only: wave-local LDS drain, no s_barrier.
    __asm__ volatile("s_waitcnt lgkmcnt(0)" ::: "memory");

    // ---- Phase B: wave wv handles 16-point tiles wv*4 .. wv*4+3 ----
#pragma unroll
    for (int t4 = 0; t4 < 4; ++t4) {
        const int t  = wv * 4 + t4;
        const int c0 = t * 128 + q * 16 + n16;  // khalf 0
        const int c1 = c0 + 64;                 // khalf 1
        OctU a0u, a1u;                          // C^T fragments (B operand)
        a0u.u4 = ldsA[c0 + (c0 >> 3)];
        a1u.u4 = ldsA[c1 + (c1 >> 3)];
        f32x4 acc[4];
#pragma unroll
        for (int ot = 0; ot < 4; ++ot) {
            acc[ot] = (f32x4){0.f, 0.f, 0.f, 0.f};
            // Swapped operands: D = (W2slice)^T * (Cslice)^T = OUT^T tile.
            acc[ot] = __builtin_amdgcn_mfma_f32_16x16x32_bf16(wfrag[0][ot], a0u.v, acc[ot], 0, 0, 0);
            acc[ot] = __builtin_amdgcn_mfma_f32_16x16x32_bf16(wfrag[1][ot], a1u.v, acc[ot], 0, 0, 0);
        }
        // D': lane holds OUT[p = t*16 + n16][o = ot*16 + q*4 + r], r=0..3
        // -> one aligned float4 per ot, write-once so nontemporal.
        f32x4* dst = (f32x4*)(out + (base + t * 16 + n16) * 64);
#pragma unroll
        for (int ot = 0; ot < 4; ++ot) {
            __builtin_nontemporal_store(acc[ot], dst + ot * 4 + q);
        }
    }
}

extern "C" void kernel_launch(void* const* d_in, const int* in_sizes, int n_in,
                              void* d_out, int out_size, void* d_ws, size_t ws_size,
                              hipStream_t stream) {
    const float* x     = (const float*)d_in[0];
    const float* kp    = (const float*)d_in[1];
    const float* w     = (const float*)d_in[2];
    const float* sigma = (const float*)d_in[3];
    float* out = (float*)d_out;

    const int npoints = in_sizes[0] / 3;      // B*N = 524288
    const int blocks  = npoints / 256;        // 2048, exact
    kpconv_mfma<<<blocks, 256, 0, stream>>>(x, kp, w, sigma, out);
}

// Round 2
// 158.946 us; speedup vs baseline: 1.0680x; 1.0680x over previous
//
#include <hip/hip_runtime.h>

// KPConv as bf16 MFMA GEMM: OUT[p,o] = sum_j C[p,j] * W2[j,o]
//   j = k*3+i (48, padded to 64), C[p,j] = g[p,k]*x[p,i], W2 = weights flat [48][64].
// Block = 256 threads = 256 points. Phase A: per-thread C-row -> LDS in MFMA
// fragment layout. Phase B: 4 waves x 4 tiles, OPERAND-SWAPPED MFMA so D = OUT^T
// tile: lane holds out[p][o..o+3] contiguous -> one float4 store per (tile,ot).
// R1 post-mortem: nontemporal stores + barrier removal regressed 144->170us;
// this version keeps ONLY the vectorized-store win (plain stores, barrier back).

typedef __bf16  bf16x8 __attribute__((ext_vector_type(8)));
typedef float   f32x4  __attribute__((ext_vector_type(4)));
typedef unsigned int   u32x4  __attribute__((ext_vector_type(4)));

union OctU {
    unsigned short s[8];
    u32x4          u4;
    bf16x8         v;
};

__global__ __launch_bounds__(256) void kpconv_mfma(
    const float* __restrict__ x,       // [P][3]
    const float* __restrict__ kp,      // [16][3]
    const float* __restrict__ w,       // [48][64] (= [16][3][64])
    const float* __restrict__ sigma,   // [1]
    float* __restrict__ out)           // [P][64]
{
    // 2048 chunks of 16B (16 tiles * 2 khalf * 4 quad * 16 m) + pad every 8
    __shared__ u32x4 ldsA[2304];

    const int tid  = threadIdx.x;
    const int lane = tid & 63;
    const int wv   = tid >> 6;
    const int q    = lane >> 4;   // quad within wave
    const int n16  = lane & 15;
    const long long base = (long long)blockIdx.x * 256;

    // ---- W fragments (weights), resident in VGPRs for the whole block ----
    // Used as the MFMA *A* operand (A/B lane layouts are symmetric):
    // A[row = n16 -> o - ot*16][k = q*8+j -> j' - h*32], value = W2[j'][o] (W2^T).
    bf16x8 wfrag[2][4];
#pragma unroll
    for (int h = 0; h < 2; ++h) {
#pragma unroll
        for (int ot = 0; ot < 4; ++ot) {
            OctU o;
#pragma unroll
            for (int j = 0; j < 8; ++j) {
                int kk = h * 32 + q * 8 + j;
                float v = (kk < 48) ? w[kk * 64 + ot * 16 + n16] : 0.0f;
                o.v[j] = (__bf16)v;   // native cast -> v_cvt_pk_bf16_f32 pairs
            }
            wfrag[h][ot] = o.v;
        }
    }

    // ---- Phase A: this thread's point -> bf16 C-row in LDS ----
    {
        const float sg = sigma[0];
        // exp(-0.5*d2/s^2) = exp2(d2 * (-0.5*log2e)/s^2)
        const float scale = -0.72134752f / (sg * sg);
        const long long p = base + tid;
        float xv[3];
        xv[0] = x[p * 3 + 0];
        xv[1] = x[p * 3 + 1];
        xv[2] = x[p * 3 + 2];
        float g[16];
#pragma unroll
        for (int k = 0; k < 16; ++k) {
            float dx = xv[0] - kp[k * 3 + 0];
            float dy = xv[1] - kp[k * 3 + 1];
            float dz = xv[2] - kp[k * 3 + 2];
            float d2 = dx * dx + dy * dy + dz * dz;
            g[k] = exp2f(d2 * scale);
        }
        const int tile = tid >> 4;
        const int m    = tid & 15;
#pragma unroll
        for (int o = 0; o < 8; ++o) {      // octet o covers j = 8o..8o+7
            OctU ou;
#pragma unroll
            for (int j8 = 0; j8 < 8; ++j8) {
                int j = o * 8 + j8;
                ou.v[j8] = (j < 48) ? (__bf16)(g[j / 3] * xv[j % 3])
                                    : (__bf16)0.0f;  // zero K-pad (LDS is poison!)
            }
            int chunk = tile * 128 + (o >> 2) * 64 + (o & 3) * 16 + m;
            ldsA[chunk + (chunk >> 3)] = ou.u4;
        }
    }
    __syncthreads();

    // ---- Phase B: wave wv handles 16-point tiles wv*4 .. wv*4+3 ----
#pragma unroll
    for (int t4 = 0; t4 < 4; ++t4) {
        const int t  = wv * 4 + t4;
        const int c0 = t * 128 + q * 16 + n16;  // khalf 0
        const int c1 = c0 + 64;                 // khalf 1
        OctU a0u, a1u;                          // C^T fragments (B operand)
        a0u.u4 = ldsA[c0 + (c0 >> 3)];
        a1u.u4 = ldsA[c1 + (c1 >> 3)];
        f32x4 acc[4];
#pragma unroll
        for (int ot = 0; ot < 4; ++ot) {
            acc[ot] = (f32x4){0.f, 0.f, 0.f, 0.f};
            // Swapped operands: D = (W2slice)^T * (Cslice)^T = OUT^T tile.
            acc[ot] = __builtin_amdgcn_mfma_f32_16x16x32_bf16(wfrag[0][ot], a0u.v, acc[ot], 0, 0, 0);
            acc[ot] = __builtin_amdgcn_mfma_f32_16x16x32_bf16(wfrag[1][ot], a1u.v, acc[ot], 0, 0, 0);
        }
        // D: lane holds OUT[p = t*16 + n16][o = ot*16 + q*4 + r], r=0..3
        // -> one aligned float4 per ot, plain (cache-default) store so L2
        //    write-combining assembles full 128B lines (R1: nt regressed).
        f32x4* dst = (f32x4*)(out + (base + t * 16 + n16) * 64);
#pragma unroll
        for (int ot = 0; ot < 4; ++ot) {
            dst[ot * 4 + q] = acc[ot];
        }
    }
}

extern "C" void kernel_launch(void* const* d_in, const int* in_sizes, int n_in,
                              void* d_out, int out_size, void* d_ws, size_t ws_size,
                              hipStream_t stream) {
    const float* x     = (const float*)d_in[0];
    const float* kp    = (const float*)d_in[1];
    const float* w     = (const float*)d_in[2];
    const float* sigma = (const float*)d_in[3];
    float* out = (float*)d_out;

    const int npoints = in_sizes[0] / 3;      // B*N = 524288
    const int blocks  = npoints / 256;        // 2048, exact
    kpconv_mfma<<<blocks, 256, 0, stream>>>(x, kp, w, sigma, out);
}

// Round 3
// 153.981 us; speedup vs baseline: 1.1025x; 1.0322x over previous
//
#include <hip/hip_runtime.h>

// KPConv as bf16 MFMA GEMM, LDS-FREE / BARRIER-FREE.
//   OUT[p,o] = sum_{k,i} g[p,k] * x[p,i] * W[k,i,o],  16x16x32 bf16 MFMA.
// Key idea: the GEMM K-dim (64 slots, 48 real) can be permuted arbitrarily as
// long as A and B agree. Permutation pi(slot h,q,j):
//   octet c = 4h+q  ->  kernel points 2c (j=0..2, i=j) and 2c+1 (j=3..5, i=j-3),
//   j=6,7 -> zero pad (on BOTH operands).
// Then lane (q,n16)'s A-octets depend on only 4 kernel points -> fragments are
// computed directly in registers (4 exp2/round). No LDS redistribution, no
// __syncthreads (which drains vmcnt(0)!), no store-burst-at-block-end: each
// wave free-runs 4 rounds of {gauss VALU -> 8 MFMA -> 16 stores}, so stores
// drain continuously under the next round's VALU. R0/R2 post-mortem showed
// store WIDTH doesn't matter; this attacks store DUTY CYCLE instead.

typedef __bf16  bf16x8 __attribute__((ext_vector_type(8)));
typedef float   f32x4  __attribute__((ext_vector_type(4)));

union OctU { unsigned short s[8]; bf16x8 v; };

__global__ __launch_bounds__(256) void kpconv_mfma(
    const float* __restrict__ x,       // [P][3]
    const float* __restrict__ kp,      // [16][3]
    const float* __restrict__ w,       // [48][64] (= [16][3][64])
    const float* __restrict__ sigma,   // [1]
    float* __restrict__ out)           // [P][64]
{
    const int tid  = threadIdx.x;
    const int lane = tid & 63;
    const int wv   = tid >> 6;
    const int q    = lane >> 4;   // quad within wave
    const int n16  = lane & 15;
    const long long base = (long long)blockIdx.x * 256;

    // ---- this lane's 4 kernel points: 2q, 2q+1 (h=0), 8+2q, 8+2q+1 (h=1) ----
    float kpt[4][3];
#pragma unroll
    for (int e = 0; e < 4; ++e) {
        const int kpi = (e >> 1) * 8 + 2 * q + (e & 1);
#pragma unroll
        for (int d = 0; d < 3; ++d) kpt[e][d] = kp[kpi * 3 + d];
    }

    // ---- B operand (weights) in the SAME pi slot order, resident in VGPRs ----
    // B[slot(h,q,j)][n = ot*16+n16] = w[(kpoint*3+i)*64 + n], 0 for j=6,7.
    bf16x8 bfrag[2][4];
#pragma unroll
    for (int h = 0; h < 2; ++h) {
#pragma unroll
        for (int ot = 0; ot < 4; ++ot) {
            OctU o;
#pragma unroll
            for (int j = 0; j < 8; ++j) {
                float v = 0.0f;
                if (j < 6) {
                    const int kpi = h * 8 + 2 * q + (j >= 3);
                    const int i   = (j >= 3) ? (j - 3) : j;
                    v = w[(kpi * 3 + i) * 64 + ot * 16 + n16];
                }
                o.v[j] = (__bf16)v;
            }
            bfrag[h][ot] = o.v;
        }
    }

    const float sg = sigma[0];
    // exp(-0.5*d2/s^2) = exp2(d2 * (-0.5*log2e)/s^2)
    const float scale = -0.72134752f / (sg * sg);

    // ---- preload x for all 4 rounds (round t4's point: base+wv*64+t4*16+n16;
    //      all 4 q-lanes read the same point -> L1 broadcast) ----
    float xv[4][3];
#pragma unroll
    for (int t4 = 0; t4 < 4; ++t4) {
        const long long p = base + wv * 64 + t4 * 16 + n16;
#pragma unroll
        for (int d = 0; d < 3; ++d) xv[t4][d] = x[p * 3 + d];
    }

    // ---- 4 independent rounds; no syncs of any kind between them ----
#pragma unroll
    for (int t4 = 0; t4 < 4; ++t4) {
        float g[4];
#pragma unroll
        for (int e = 0; e < 4; ++e) {
            const float dx = xv[t4][0] - kpt[e][0];
            const float dy = xv[t4][1] - kpt[e][1];
            const float dz = xv[t4][2] - kpt[e][2];
            g[e] = exp2f((dx * dx + dy * dy + dz * dz) * scale);
        }
        // A[m=n16][slot]: j<3 -> g[2h]*x_i, 3<=j<6 -> g[2h+1]*x_{j-3}, j>=6 -> 0
        OctU a0, a1;
#pragma unroll
        for (int j = 0; j < 3; ++j) {
            a0.v[j]     = (__bf16)(g[0] * xv[t4][j]);
            a0.v[j + 3] = (__bf16)(g[1] * xv[t4][j]);
            a1.v[j]     = (__bf16)(g[2] * xv[t4][j]);
            a1.v[j + 3] = (__bf16)(g[3] * xv[t4][j]);
        }
        a0.v[6] = a0.v[7] = (__bf16)0.0f;
        a1.v[6] = a1.v[7] = (__bf16)0.0f;

        f32x4 acc[4];
#pragma unroll
        for (int ot = 0; ot < 4; ++ot) {
            acc[ot] = (f32x4){0.f, 0.f, 0.f, 0.f};
            acc[ot] = __builtin_amdgcn_mfma_f32_16x16x32_bf16(a0.v, bfrag[0][ot], acc[ot], 0, 0, 0);
            acc[ot] = __builtin_amdgcn_mfma_f32_16x16x32_bf16(a1.v, bfrag[1][ot], acc[ot], 0, 0, 0);
        }
        // D: lane holds OUT[row = q*4+r][col = ot*16+n16] of this 16-pt tile
        const long long prow = base + wv * 64 + t4 * 16 + q * 4;
#pragma unroll
        for (int ot = 0; ot < 4; ++ot) {
#pragma unroll
            for (int r = 0; r < 4; ++r) {
                out[(prow + r) * 64 + ot * 16 + n16] = acc[ot][r];
            }
        }
    }
}

extern "C" void kernel_launch(void* const* d_in, const int* in_sizes, int n_in,
                              void* d_out, int out_size, void* d_ws, size_t ws_size,
                              hipStream_t stream) {
    const float* x     = (const float*)d_in[0];
    const float* kp    = (const float*)d_in[1];
    const float* w     = (const float*)d_in[2];
    const float* sigma = (const float*)d_in[3];
    float* out = (float*)d_out;

    const int npoints = in_sizes[0] / 3;      // B*N = 524288
    const int blocks  = npoints / 256;        // 2048, exact
    kpconv_mfma<<<blocks, 256, 0, stream>>>(x, kp, w, sigma, out);
}

// Round 4
// 147.943 us; speedup vs baseline: 1.1475x; 1.0408x over previous
//
#include <hip/hip_runtime.h>

// KPConv as bf16 MFMA GEMM, LDS-free fragments (R3) + LDS-STAGED LINEAR EPILOGUE.
//   OUT[p,o] = sum_{k,i} g[p,k] * x[p,i] * W[k,i,o],  16x16x32 bf16 MFMA.
// R3 post-mortem: barrier/LDS/occupancy changes are all ~neutral; the one axis
// never tested is store-segment shape. All prior epilogues store 64B scattered
// segments (MFMA D-layout); the 6.8TB/s fill stores 1KB single segments.
// This version stages each 16x64 f32 tile in a WAVE-PRIVATE LDS buffer
// (row stride 68 dwords: writes 2-way/free, reads uniform 8/bank), re-reads it
// linearly, and stores with global_store_dwordx4 = one contiguous 1KB segment
// per instruction, byte-identical pattern to the fill. No barriers anywhere.

typedef __bf16  bf16x8 __attribute__((ext_vector_type(8)));
typedef float   f32x4  __attribute__((ext_vector_type(4)));

union OctU { unsigned short s[8]; bf16x8 v; };

#define STG_STRIDE 68   // 16 rows x 68 dwords = 272B rows (16B-aligned), 4352B/wave

__global__ __launch_bounds__(256) void kpconv_mfma(
    const float* __restrict__ x,       // [P][3]
    const float* __restrict__ kp,      // [16][3]
    const float* __restrict__ w,       // [48][64] (= [16][3][64])
    const float* __restrict__ sigma,   // [1]
    float* __restrict__ out)           // [P][64]
{
    __shared__ float stg[4 * 16 * STG_STRIDE];  // 17408 B, wave-private quarters

    const int tid  = threadIdx.x;
    const int lane = tid & 63;
    const int wv   = tid >> 6;
    const int q    = lane >> 4;   // quad within wave
    const int n16  = lane & 15;
    const long long base = (long long)blockIdx.x * 256;

    float* const swv = &stg[wv * 16 * STG_STRIDE];

    // ---- this lane's 4 kernel points: 2q, 2q+1 (h=0), 8+2q, 8+2q+1 (h=1) ----
    float kpt[4][3];
#pragma unroll
    for (int e = 0; e < 4; ++e) {
        const int kpi = (e >> 1) * 8 + 2 * q + (e & 1);
#pragma unroll
        for (int d = 0; d < 3; ++d) kpt[e][d] = kp[kpi * 3 + d];
    }

    // ---- B operand (weights) in the pi slot order, resident in VGPRs ----
    // pi(slot h,q,j): octet c=4h+q -> kpoints 2c (j=0..2, i=j), 2c+1 (j=3..5),
    // j=6,7 zero pad on BOTH operands.
    bf16x8 bfrag[2][4];
#pragma unroll
    for (int h = 0; h < 2; ++h) {
#pragma unroll
        for (int ot = 0; ot < 4; ++ot) {
            OctU o;
#pragma unroll
            for (int j = 0; j < 8; ++j) {
                float v = 0.0f;
                if (j < 6) {
                    const int kpi = h * 8 + 2 * q + (j >= 3);
                    const int i   = (j >= 3) ? (j - 3) : j;
                    v = w[(kpi * 3 + i) * 64 + ot * 16 + n16];
                }
                o.v[j] = (__bf16)v;
            }
            bfrag[h][ot] = o.v;
        }
    }

    const float sg = sigma[0];
    // exp(-0.5*d2/s^2) = exp2(d2 * (-0.5*log2e)/s^2)
    const float scale = -0.72134752f / (sg * sg);

    // ---- preload x for all 4 rounds (all 4 q-lanes read same point: L1 bcast)
    float xv[4][3];
#pragma unroll
    for (int t4 = 0; t4 < 4; ++t4) {
        const long long p = base + wv * 64 + t4 * 16 + n16;
#pragma unroll
        for (int d = 0; d < 3; ++d) xv[t4][d] = x[p * 3 + d];
    }

    // ---- 4 independent rounds; no block-level syncs anywhere ----
#pragma unroll
    for (int t4 = 0; t4 < 4; ++t4) {
        float g[4];
#pragma unroll
        for (int e = 0; e < 4; ++e) {
            const float dx = xv[t4][0] - kpt[e][0];
            const float dy = xv[t4][1] - kpt[e][1];
            const float dz = xv[t4][2] - kpt[e][2];
            g[e] = exp2f((dx * dx + dy * dy + dz * dz) * scale);
        }
        // A[m=n16][slot]: j<3 -> g[2h]*x_i, 3<=j<6 -> g[2h+1]*x_{j-3}, j>=6 -> 0
        OctU a0, a1;
#pragma unroll
        for (int j = 0; j < 3; ++j) {
            a0.v[j]     = (__bf16)(g[0] * xv[t4][j]);
            a0.v[j + 3] = (__bf16)(g[1] * xv[t4][j]);
            a1.v[j]     = (__bf16)(g[2] * xv[t4][j]);
            a1.v[j + 3] = (__bf16)(g[3] * xv[t4][j]);
        }
        a0.v[6] = a0.v[7] = (__bf16)0.0f;
        a1.v[6] = a1.v[7] = (__bf16)0.0f;

        f32x4 acc[4];
#pragma unroll
        for (int ot = 0; ot < 4; ++ot) {
            acc[ot] = (f32x4){0.f, 0.f, 0.f, 0.f};
            acc[ot] = __builtin_amdgcn_mfma_f32_16x16x32_bf16(a0.v, bfrag[0][ot], acc[ot], 0, 0, 0);
            acc[ot] = __builtin_amdgcn_mfma_f32_16x16x32_bf16(a1.v, bfrag[1][ot], acc[ot], 0, 0, 0);
        }

        // ---- stage tile to wave-private LDS (D-layout -> row-major) ----
        // D: lane holds OUT[row = q*4+r][col = ot*16+n16]; banks: rows differ by
        // 68*4 = 16q mod 32 -> exact 2-way (free).
#pragma unroll
        for (int ot = 0; ot < 4; ++ot) {
#pragma unroll
            for (int r = 0; r < 4; ++r) {
                swv[(q * 4 + r) * STG_STRIDE + ot * 16 + n16] = acc[ot][r];
            }
        }
        // same-wave RAW on LDS: hardware/compiler lgkmcnt ordering, no barrier.

        // ---- linear re-read + contiguous 1KB-per-instruction stores ----
        // Instr s: 64 lanes cover rows s*4..s*4+3 (16B/lane, ascending) = 1KB.
        const long long trow = base + wv * 64 + t4 * 16;
#pragma unroll
        for (int s = 0; s < 4; ++s) {
            const float* sp = &swv[(s * 4 + q) * STG_STRIDE + n16 * 4];
            f32x4 vv = *reinterpret_cast<const f32x4*>(
                __builtin_assume_aligned(sp, 16));
            float* dp = out + (trow + s * 4 + q) * 64 + n16 * 4;
            *reinterpret_cast<f32x4*>(__builtin_assume_aligned(dp, 16)) = vv;
        }
    }
}

extern "C" void kernel_launch(void* const* d_in, const int* in_sizes, int n_in,
                              void* d_out, int out_size, void* d_ws, size_t ws_size,
                              hipStream_t stream) {
    const float* x     = (const float*)d_in[0];
    const float* kp    = (const float*)d_in[1];
    const float* w     = (const float*)d_in[2];
    const float* sigma = (const float*)d_in[3];
    float* out = (float*)d_out;

    const int npoints = in_sizes[0] / 3;      // B*N = 524288
    const int blocks  = npoints / 256;        // 2048, exact
    kpconv_mfma<<<blocks, 256, 0, stream>>>(x, kp, w, sigma, out);
}

// Round 5
// 144.503 us; speedup vs baseline: 1.1748x; 1.0238x over previous
//
#include <hip/hip_runtime.h>

// KPConv bf16 MFMA GEMM — PERSISTENT blocks + chunk-level software pipeline.
//   OUT[p,o] = sum_{k,i} g[p,k] * x[p,i] * W[k,i,o],  16x16x32 bf16 MFMA.
// R0-R4 post-mortem: store width/segment/barrier/LDS micro-structure all
// ~neutral; kernel stuck ~3x over traffic floor. Common factor was 8 short
// block generations per CU, each with a ~90-load prologue and lockstep store
// bursts -> HBM write pipe idle most of the time. This version: 512 blocks
// (2/CU), 4 chunks of 256 points each (contiguous 256KB out region/block),
// weights/kpt loaded ONCE, x double-buffered one chunk ahead (static-indexed
// regs, chunk loop fully unrolled). Stores flow continuously; no syncs.

typedef __bf16  bf16x8 __attribute__((ext_vector_type(8)));
typedef float   f32x4  __attribute__((ext_vector_type(4)));

union OctU { unsigned short s[8]; bf16x8 v; };

#define STG_STRIDE 68   // 16 rows x 68 dwords: ds_writes 2-way (free), reads uniform
#define CHUNKS 4

__global__ __launch_bounds__(256) void kpconv_mfma(
    const float* __restrict__ x,       // [P][3]
    const float* __restrict__ kp,      // [16][3]
    const float* __restrict__ w,       // [48][64] (= [16][3][64])
    const float* __restrict__ sigma,   // [1]
    float* __restrict__ out)           // [P][64]
{
    __shared__ float stg[4 * 16 * STG_STRIDE];  // wave-private quarters

    const int tid  = threadIdx.x;
    const int lane = tid & 63;
    const int wv   = tid >> 6;
    const int q    = lane >> 4;   // quad within wave
    const int n16  = lane & 15;
    const long long bbase = (long long)blockIdx.x * (256 * CHUNKS);

    float* const swv = &stg[wv * 16 * STG_STRIDE];

    // ---- this lane's 4 kernel points: 2q, 2q+1 (h=0), 8+2q, 8+2q+1 (h=1) ----
    float kpt[4][3];
#pragma unroll
    for (int e = 0; e < 4; ++e) {
        const int kpi = (e >> 1) * 8 + 2 * q + (e & 1);
#pragma unroll
        for (int d = 0; d < 3; ++d) kpt[e][d] = kp[kpi * 3 + d];
    }

    // ---- B operand (weights) in pi slot order, resident in VGPRs, ONCE ----
    // pi(slot h,q,j): octet c=4h+q -> kpoints 2c (j=0..2, i=j), 2c+1 (j=3..5),
    // j=6,7 zero pad on BOTH operands.
    bf16x8 bfrag[2][4];
#pragma unroll
    for (int h = 0; h < 2; ++h) {
#pragma unroll
        for (int ot = 0; ot < 4; ++ot) {
            OctU o;
#pragma unroll
            for (int j = 0; j < 8; ++j) {
                float v = 0.0f;
                if (j < 6) {
                    const int kpi = h * 8 + 2 * q + (j >= 3);
                    const int i   = (j >= 3) ? (j - 3) : j;
                    v = w[(kpi * 3 + i) * 64 + ot * 16 + n16];
                }
                o.v[j] = (__bf16)v;
            }
            bfrag[h][ot] = o.v;
        }
    }

    const float sg = sigma[0];
    // exp(-0.5*d2/s^2) = exp2(d2 * (-0.5*log2e)/s^2)
    const float scale = -0.72134752f / (sg * sg);

    // ---- x double buffer: chunk 0 now; chunk c+1 prefetched under chunk c ----
    float xv[2][4][3];   // all indices compile-time (loop fully unrolled)
#pragma unroll
    for (int t4 = 0; t4 < 4; ++t4) {
        const long long p = bbase + wv * 64 + t4 * 16 + n16;
#pragma unroll
        for (int d = 0; d < 3; ++d) xv[0][t4][d] = x[p * 3 + d];
    }

#pragma unroll
    for (int c = 0; c < CHUNKS; ++c) {
        const int cur = c & 1;
        const int nxt = cur ^ 1;
        // issue next chunk's x loads FIRST; latency hides under this chunk
        if (c + 1 < CHUNKS) {
#pragma unroll
            for (int t4 = 0; t4 < 4; ++t4) {
                const long long p = bbase + (long long)(c + 1) * 256 + wv * 64 + t4 * 16 + n16;
#pragma unroll
                for (int d = 0; d < 3; ++d) xv[nxt][t4][d] = x[p * 3 + d];
            }
        }
        const long long cbase = bbase + (long long)c * 256;

#pragma unroll
        for (int t4 = 0; t4 < 4; ++t4) {
            float g[4];
#pragma unroll
            for (int e = 0; e < 4; ++e) {
                const float dx = xv[cur][t4][0] - kpt[e][0];
                const float dy = xv[cur][t4][1] - kpt[e][1];
                const float dz = xv[cur][t4][2] - kpt[e][2];
                g[e] = exp2f((dx * dx + dy * dy + dz * dz) * scale);
            }
            // A[m=n16][slot]: j<3 -> g[2h]*x_i, 3<=j<6 -> g[2h+1]*x_{j-3}, j>=6 -> 0
            OctU a0, a1;
#pragma unroll
            for (int j = 0; j < 3; ++j) {
                a0.v[j]     = (__bf16)(g[0] * xv[cur][t4][j]);
                a0.v[j + 3] = (__bf16)(g[1] * xv[cur][t4][j]);
                a1.v[j]     = (__bf16)(g[2] * xv[cur][t4][j]);
                a1.v[j + 3] = (__bf16)(g[3] * xv[cur][t4][j]);
            }
            a0.v[6] = a0.v[7] = (__bf16)0.0f;
            a1.v[6] = a1.v[7] = (__bf16)0.0f;

            f32x4 acc[4];
#pragma unroll
            for (int ot = 0; ot < 4; ++ot) {
                acc[ot] = (f32x4){0.f, 0.f, 0.f, 0.f};
                acc[ot] = __builtin_amdgcn_mfma_f32_16x16x32_bf16(a0.v, bfrag[0][ot], acc[ot], 0, 0, 0);
                acc[ot] = __builtin_amdgcn_mfma_f32_16x16x32_bf16(a1.v, bfrag[1][ot], acc[ot], 0, 0, 0);
            }

            // stage tile (D-layout -> row-major) in wave-private LDS; same-wave
            // DS ops are in-order, so no barriers for RAW/WAR across rounds.
#pragma unroll
            for (int ot = 0; ot < 4; ++ot) {
#pragma unroll
                for (int r = 0; r < 4; ++r) {
                    swv[(q * 4 + r) * STG_STRIDE + ot * 16 + n16] = acc[ot][r];
                }
            }
            // linear re-read -> 4 x global_store_dwordx4, 1KB contiguous each
            const long long trow = cbase + wv * 64 + t4 * 16;
#pragma unroll
            for (int s = 0; s < 4; ++s) {
                const float* sp = &swv[(s * 4 + q) * STG_STRIDE + n16 * 4];
                f32x4 vv = *reinterpret_cast<const f32x4*>(
                    __builtin_assume_aligned(sp, 16));
                float* dp = out + (trow + s * 4 + q) * 64 + n16 * 4;
                *reinterpret_cast<f32x4*>(__builtin_assume_aligned(dp, 16)) = vv;
            }
        }
    }
}

extern "C" void kernel_launch(void* const* d_in, const int* in_sizes, int n_in,
                              void* d_out, int out_size, void* d_ws, size_t ws_size,
                              hipStream_t stream) {
    const float* x     = (const float*)d_in[0];
    const float* kp    = (const float*)d_in[1];
    const float* w     = (const float*)d_in[2];
    const float* sigma = (const float*)d_in[3];
    float* out = (float*)d_out;

    const int npoints = in_sizes[0] / 3;          // B*N = 524288
    const int blocks  = npoints / (256 * CHUNKS); // 512, exact
    kpconv_mfma<<<blocks, 256, 0, stream>>>(x, kp, w, sigma, out);
}